// Round 1
// baseline (2198.281 us; speedup 1.0000x reference)
//
#include <hip/hip_runtime.h>

// Transformer block: B=4096, T=64, C=64, H=8, hs=8, FF=256. fp32 in/out.
// One block per batch element; 256 threads (4 waves). All activations in LDS.

#define EPS 1e-5f
#define ATTN_SCALE 0.125f   // C^-0.5 = 64^-0.5

// LDS float offsets (phase-overlaid):
#define OFF_Q   0       // 4096: q[t*64+j]            ; later xres[t*64+j]
#define OFF_KT  4096    // 4160: kT[j*65+t]           ; later h2[t*64+c]
#define OFF_XS  8256    // 4096: x[t*64+c]
#define OFF_HS  12352   // 4352: h(LN1)[t*64+c] then ac[t*68+j]
#define OFF_AC  12352
#define OFF_V   16704   // 4096: v[t*64+j]
#define OFF_SC  20800   // 4160: scores/probs sc[t*65+s]
#define OFF_U   8256    // 16384: u[t*256+m] (overlays XS,HS/AC,V,SC after they are dead)
#define OFF_XR  0
#define OFF_H2  4096
#define NSMEM   24960   // floats = 99840 bytes

__device__ __forceinline__ void layernorm64(float* sm, int off_in, int off_out,
                                            const float* __restrict__ g,
                                            const float* __restrict__ be, int tid) {
    // 4 threads per row; 16 elems each; combine via shfl_xor(1,2)
    int t = tid >> 2, qtr = tid & 3;
    const int base = off_in + t * 64;
    float s1 = 0.f, s2 = 0.f;
#pragma unroll
    for (int i = 0; i < 16; ++i) {
        float v = sm[base + qtr * 16 + i];
        s1 += v; s2 += v * v;
    }
    s1 += __shfl_xor(s1, 1); s1 += __shfl_xor(s1, 2);
    s2 += __shfl_xor(s2, 1); s2 += __shfl_xor(s2, 2);
    float mu = s1 * 0.015625f;
    float rstd = rsqrtf(s2 * 0.015625f - mu * mu + EPS);
#pragma unroll
    for (int i = 0; i < 16; ++i) {
        int c = qtr * 16 + i;
        float v = sm[base + c];
        sm[off_out + t * 64 + c] = (v - mu) * rstd * g[c] + be[c];
    }
}

__global__ __launch_bounds__(256) void block_kernel(
    const float* __restrict__ x,  const float* __restrict__ Wq,
    const float* __restrict__ Wk, const float* __restrict__ Wv,
    const float* __restrict__ Wo, const float* __restrict__ bo,
    const float* __restrict__ W1, const float* __restrict__ b1,
    const float* __restrict__ W2, const float* __restrict__ b2,
    const float* __restrict__ g1, const float* __restrict__ be1,
    const float* __restrict__ g2, const float* __restrict__ be2,
    float* __restrict__ out)
{
    __shared__ float sm[NSMEM];
    const int b    = blockIdx.x;
    const int tid  = threadIdx.x;
    const int lane = tid & 63;
    const int wv   = tid >> 6;          // wave 0..3
    const float* xb = x + (size_t)b * 4096;

    // ---- load x (coalesced float4) ----
#pragma unroll
    for (int i = 0; i < 4; ++i) {
        int idx = (i * 256 + tid) * 4;
        *(float4*)&sm[OFF_XS + idx] = *(const float4*)(xb + idx);
    }
    __syncthreads();

    // ---- LN1: xs -> hs ----
    layernorm64(sm, OFF_XS, OFF_HS, g1, be1, tid);
    __syncthreads();

    // ---- QKV projections: lane=j (output col), 16 rows/thread ----
    {
        const int j = lane;
        const int tbase = wv * 16;
        float qa[16], ka[16], va[16];
#pragma unroll
        for (int i = 0; i < 16; ++i) { qa[i] = 0.f; ka[i] = 0.f; va[i] = 0.f; }
        for (int c = 0; c < 64; c += 4) {
            float wq0 = Wq[(c + 0) * 64 + j], wq1 = Wq[(c + 1) * 64 + j];
            float wq2 = Wq[(c + 2) * 64 + j], wq3 = Wq[(c + 3) * 64 + j];
            float wk0 = Wk[(c + 0) * 64 + j], wk1 = Wk[(c + 1) * 64 + j];
            float wk2 = Wk[(c + 2) * 64 + j], wk3 = Wk[(c + 3) * 64 + j];
            float wv0 = Wv[(c + 0) * 64 + j], wv1 = Wv[(c + 1) * 64 + j];
            float wv2 = Wv[(c + 2) * 64 + j], wv3 = Wv[(c + 3) * 64 + j];
#pragma unroll
            for (int i = 0; i < 16; ++i) {
                float4 h4 = *(const float4*)&sm[OFF_HS + (tbase + i) * 64 + c]; // broadcast
                qa[i] = fmaf(h4.x, wq0, fmaf(h4.y, wq1, fmaf(h4.z, wq2, fmaf(h4.w, wq3, qa[i]))));
                ka[i] = fmaf(h4.x, wk0, fmaf(h4.y, wk1, fmaf(h4.z, wk2, fmaf(h4.w, wk3, ka[i]))));
                va[i] = fmaf(h4.x, wv0, fmaf(h4.y, wv1, fmaf(h4.z, wv2, fmaf(h4.w, wv3, va[i]))));
            }
        }
#pragma unroll
        for (int i = 0; i < 16; ++i) {
            int t = tbase + i;
            sm[OFF_Q  + t * 64 + j] = qa[i];
            sm[OFF_KT + j * 65 + t] = ka[i];   // transposed, pad 65 -> conflict-free
            sm[OFF_V  + t * 64 + j] = va[i];
        }
    }
    __syncthreads();

    // ---- attention, per head ----
    for (int hh = 0; hh < 8; ++hh) {
        // scores + softmax: wave owns rows t = wv*16 + i; lane = s
#pragma unroll 1
        for (int i = 0; i < 16; ++i) {
            int t = wv * 16 + i;
            int s = lane;
            float4 qa = *(const float4*)&sm[OFF_Q + t * 64 + hh * 8];      // broadcast
            float4 qb = *(const float4*)&sm[OFF_Q + t * 64 + hh * 8 + 4];
            const int kb = OFF_KT + hh * 8 * 65 + s;                        // lane-major
            float acc = qa.x * sm[kb]       + qa.y * sm[kb + 65]
                      + qa.z * sm[kb + 130] + qa.w * sm[kb + 195]
                      + qb.x * sm[kb + 260] + qb.y * sm[kb + 325]
                      + qb.z * sm[kb + 390] + qb.w * sm[kb + 455];
            float val = (s <= t) ? acc * ATTN_SCALE : -3.0e38f;
            float m = val;
#pragma unroll
            for (int d = 32; d > 0; d >>= 1) m = fmaxf(m, __shfl_xor(m, d));
            float e = __expf(val - m);
            float ssum = e;
#pragma unroll
            for (int d = 32; d > 0; d >>= 1) ssum += __shfl_xor(ssum, d);
            sm[OFF_SC + t * 65 + s] = e / ssum;
        }
        __syncthreads();
        // PV: 2 outputs/thread; lane bits: d = lane&7, t = o>>3
#pragma unroll
        for (int oo = 0; oo < 2; ++oo) {
            int o = tid + oo * 256;
            int t = o >> 3, d = o & 7;
            const int scb = OFF_SC + t * 65;
            const int vb  = OFF_V + hh * 8 + d;
            float acc = 0.f;
            for (int s = 0; s <= t; ++s)            // probs are 0 beyond t
                acc = fmaf(sm[scb + s], sm[vb + s * 64], acc);
            sm[OFF_AC + t * 68 + hh * 8 + d] = acc; // pad 68 -> <=2 lanes/bank
        }
        __syncthreads();
    }

    // ---- out-projection + residual: xres = x + ac@Wo + bo ----
    {
        const int j = lane;
        const int tbase = wv * 16;
        float acc[16];
#pragma unroll
        for (int i = 0; i < 16; ++i) acc[i] = 0.f;
        for (int ii = 0; ii < 64; ii += 4) {
            float w0 = Wo[(ii + 0) * 64 + j], w1 = Wo[(ii + 1) * 64 + j];
            float w2 = Wo[(ii + 2) * 64 + j], w3 = Wo[(ii + 3) * 64 + j];
#pragma unroll
            for (int i = 0; i < 16; ++i) {
                float4 a4 = *(const float4*)&sm[OFF_AC + (tbase + i) * 68 + ii];
                acc[i] = fmaf(a4.x, w0, fmaf(a4.y, w1, fmaf(a4.z, w2, fmaf(a4.w, w3, acc[i]))));
            }
        }
        float bb = bo[j];
#pragma unroll
        for (int i = 0; i < 16; ++i) {
            int t = tbase + i;
            sm[OFF_XR + t * 64 + j] = sm[OFF_XS + t * 64 + j] + acc[i] + bb;
        }
    }
    __syncthreads();

    // ---- LN2: xres -> h2 ----
    layernorm64(sm, OFF_XR, OFF_H2, g2, be2, tid);
    __syncthreads();

    // ---- FF1: u = relu(h2 @ W1 + b1), 256-wide ----
    {
        const int m0 = lane;
        const int tbase = wv * 16;
        for (int mi = 0; mi < 4; ++mi) {
            int m = m0 + mi * 64;
            float acc[16];
#pragma unroll
            for (int i = 0; i < 16; ++i) acc[i] = 0.f;
            for (int c = 0; c < 64; c += 4) {
                float w0 = W1[(c + 0) * 256 + m], w1 = W1[(c + 1) * 256 + m];
                float w2 = W1[(c + 2) * 256 + m], w3 = W1[(c + 3) * 256 + m];
#pragma unroll
                for (int i = 0; i < 16; ++i) {
                    float4 h4 = *(const float4*)&sm[OFF_H2 + (tbase + i) * 64 + c];
                    acc[i] = fmaf(h4.x, w0, fmaf(h4.y, w1, fmaf(h4.z, w2, fmaf(h4.w, w3, acc[i]))));
                }
            }
            float bb = b1[m];
#pragma unroll
            for (int i = 0; i < 16; ++i)
                sm[OFF_U + (tbase + i) * 256 + m] = fmaxf(acc[i] + bb, 0.f);
        }
    }
    __syncthreads();

    // ---- FF2 + residual -> global ----
    {
        const int j = lane;
        const int tbase = wv * 16;
        float acc[16];
#pragma unroll
        for (int i = 0; i < 16; ++i) acc[i] = 0.f;
        for (int m = 0; m < 256; m += 4) {
            float w0 = W2[(m + 0) * 64 + j], w1 = W2[(m + 1) * 64 + j];
            float w2 = W2[(m + 2) * 64 + j], w3 = W2[(m + 3) * 64 + j];
#pragma unroll
            for (int i = 0; i < 16; ++i) {
                float4 u4 = *(const float4*)&sm[OFF_U + (tbase + i) * 256 + m];
                acc[i] = fmaf(u4.x, w0, fmaf(u4.y, w1, fmaf(u4.z, w2, fmaf(u4.w, w3, acc[i]))));
            }
        }
        float bb = b2[j];
        float* ob = out + (size_t)b * 4096;
#pragma unroll
        for (int i = 0; i < 16; ++i) {
            int t = tbase + i;
            ob[t * 64 + j] = sm[OFF_XR + t * 64 + j] + acc[i] + bb;
        }
    }
}

extern "C" void kernel_launch(void* const* d_in, const int* in_sizes, int n_in,
                              void* d_out, int out_size, void* d_ws, size_t ws_size,
                              hipStream_t stream) {
    const float* x   = (const float*)d_in[0];
    const float* Wq  = (const float*)d_in[1];
    const float* Wk  = (const float*)d_in[2];
    const float* Wv  = (const float*)d_in[3];
    const float* Wo  = (const float*)d_in[4];
    const float* bo  = (const float*)d_in[5];
    const float* W1  = (const float*)d_in[6];
    const float* b1  = (const float*)d_in[7];
    const float* W2  = (const float*)d_in[8];
    const float* b2  = (const float*)d_in[9];
    const float* g1  = (const float*)d_in[10];
    const float* be1 = (const float*)d_in[11];
    const float* g2  = (const float*)d_in[12];
    const float* be2 = (const float*)d_in[13];
    const int nb = in_sizes[0] / 4096;   // 4096 batch elements
    block_kernel<<<dim3(nb), dim3(256), 0, stream>>>(
        x, Wq, Wk, Wv, Wo, bo, W1, b1, W2, b2, g1, be1, g2, be2, (float*)d_out);
}

// Round 2
// 338.996 us; speedup vs baseline: 6.4847x; 6.4847x over previous
//
#include <hip/hip_runtime.h>

// Transformer block B=4096,T=64,C=64,H=8,hs=8,FF=256. fp32 in/out, bf16 MFMA inside.
// One batch per block, 256 threads (4 waves). Wave w owns output rows 16w..16w+15.
// All matmuls: __builtin_amdgcn_mfma_f32_16x16x32_bf16.
// C-frag layout: col=lane&15, row=quad*4+reg.  A[m=lane&15][k=quad*8+j], B[k=quad*8+j][n=lane&15].

typedef __attribute__((ext_vector_type(8))) short short8;
typedef __attribute__((ext_vector_type(4))) float f32x4;

#define ST 72            // bf16 row stride (144B, 16B-aligned, odd*8 -> ~conflict-free)
#define OH  0            // h(LN1) [64][72]; reused as attn-concat a16; then h2(LN2)
#define OQ  4608         // q [64][72]; reused as u-chunk in FF
#define OKK 9216         // k [64][72]
#define OV  13824        // vT [64][72]  (vT[d][s])
#define OP  18432        // P (probs, per head) [64][72]
#define NSH 23040        // shorts = 46080 B -> 3 blocks/CU

__device__ __forceinline__ short f2bf(float f) {
    unsigned int u = __float_as_uint(f);
    u += 0x7fffu + ((u >> 16) & 1u);
    return (short)(u >> 16);
}

__device__ __forceinline__ f32x4 mfma16(short8 a, short8 b, f32x4 c) {
    return __builtin_amdgcn_mfma_f32_16x16x32_bf16(a, b, c, 0, 0, 0);
}

__global__ __launch_bounds__(256, 3) void block_kernel(
    const float* __restrict__ x,  const float* __restrict__ Wq,
    const float* __restrict__ Wk, const float* __restrict__ Wv,
    const float* __restrict__ Wo, const float* __restrict__ bo,
    const float* __restrict__ W1, const float* __restrict__ b1,
    const float* __restrict__ W2, const float* __restrict__ b2,
    const float* __restrict__ g1, const float* __restrict__ be1,
    const float* __restrict__ g2, const float* __restrict__ be2,
    float* __restrict__ out)
{
    __shared__ short sm[NSH];
    const int tid  = threadIdx.x;
    const int wv   = tid >> 6;
    const int lane = tid & 63;
    const int quad = lane >> 4;
    const int nn   = lane & 15;
    const int b    = blockIdx.x;
    const float* xb = x + (size_t)b * 4096;

    // ---------- phase 1: load x (regs, C-layout), LN1 -> h16 ----------
    float xr[16];                       // xr[nt*4+r] = x[t(r)][j(nt)]
    float gv[4], bv[4];
#pragma unroll
    for (int nt = 0; nt < 4; ++nt) { gv[nt] = g1[nt * 16 + nn]; bv[nt] = be1[nt * 16 + nn]; }
#pragma unroll
    for (int nt = 0; nt < 4; ++nt)
#pragma unroll
        for (int r = 0; r < 4; ++r)
            xr[nt * 4 + r] = xb[(wv * 16 + quad * 4 + r) * 64 + nt * 16 + nn];
#pragma unroll
    for (int r = 0; r < 4; ++r) {
        float s1 = 0.f, s2 = 0.f;
#pragma unroll
        for (int nt = 0; nt < 4; ++nt) { float v = xr[nt * 4 + r]; s1 += v; s2 += v * v; }
        s1 += __shfl_xor(s1, 1); s1 += __shfl_xor(s1, 2); s1 += __shfl_xor(s1, 4); s1 += __shfl_xor(s1, 8);
        s2 += __shfl_xor(s2, 1); s2 += __shfl_xor(s2, 2); s2 += __shfl_xor(s2, 4); s2 += __shfl_xor(s2, 8);
        float mu = s1 * 0.015625f;
        float rstd = rsqrtf(s2 * 0.015625f - mu * mu + 1e-5f);
        int t = wv * 16 + quad * 4 + r;
#pragma unroll
        for (int nt = 0; nt < 4; ++nt)
            sm[OH + t * ST + nt * 16 + nn] = f2bf((xr[nt * 4 + r] - mu) * rstd * gv[nt] + bv[nt]);
    }
    __syncthreads();

    // ---------- phase 2: QKV = h @ [Wq|Wk|Wv]  (wave w: col tiles 3w..3w+2) ----------
    {
        f32x4 acc[3][4];
#pragma unroll
        for (int a = 0; a < 3; ++a)
#pragma unroll
            for (int m = 0; m < 4; ++m) acc[a][m] = (f32x4){0.f, 0.f, 0.f, 0.f};
#pragma unroll
        for (int ks = 0; ks < 2; ++ks) {
            short8 af[4];
#pragma unroll
            for (int mt = 0; mt < 4; ++mt)
                af[mt] = *(const short8*)&sm[OH + (mt * 16 + nn) * ST + ks * 32 + quad * 8];
#pragma unroll
            for (int ntl = 0; ntl < 3; ++ntl) {
                int tile = wv * 3 + ntl;
                const float* Ws = (tile < 4) ? Wq : ((tile < 8) ? Wk : Wv);
                int col = (tile & 3) * 16 + nn;
                short8 bf;
#pragma unroll
                for (int j = 0; j < 8; ++j)
                    bf[j] = f2bf(Ws[(ks * 32 + quad * 8 + j) * 64 + col]);
#pragma unroll
                for (int mt = 0; mt < 4; ++mt)
                    acc[ntl][mt] = mfma16(af[mt], bf, acc[ntl][mt]);
            }
        }
#pragma unroll
        for (int ntl = 0; ntl < 3; ++ntl) {
            int tile = wv * 3 + ntl;
#pragma unroll
            for (int mt = 0; mt < 4; ++mt)
#pragma unroll
                for (int r = 0; r < 4; ++r) {
                    int row = mt * 16 + quad * 4 + r;
                    short v = f2bf(acc[ntl][mt][r]);
                    if (tile < 4)      sm[OQ  + row * ST + tile * 16 + nn] = v;
                    else if (tile < 8) sm[OKK + row * ST + (tile - 4) * 16 + nn] = v;
                    else               sm[OV  + ((tile - 8) * 16 + nn) * ST + row] = v;  // vT[d][s]
                }
        }
    }
    __syncthreads();

    // ---------- phase 3: attention (no barriers; wave w owns rows 16w..16w+15) ----------
    const f32x4 zf = {0.f, 0.f, 0.f, 0.f};
    const short8 z8 = {0, 0, 0, 0, 0, 0, 0, 0};
#pragma unroll 1
    for (int h = 0; h < 8; ++h) {
        // scores: S = q_h @ k_h^T  (K=8 zero-padded to 32; quad 0 carries data)
        short8 aq = z8;
        if (quad == 0) aq = *(const short8*)&sm[OQ + (wv * 16 + nn) * ST + h * 8];
        f32x4 sc[4];
#pragma unroll
        for (int nt = 0; nt < 4; ++nt) {
            short8 bk = z8;
            if (quad == 0) bk = *(const short8*)&sm[OKK + (nt * 16 + nn) * ST + h * 8];
            sc[nt] = mfma16(aq, bk, zf);
        }
        // softmax rows t = wv*16 + quad*4 + r (row lives in this quad's 16 lanes)
#pragma unroll
        for (int r = 0; r < 4; ++r) {
            int t = wv * 16 + quad * 4 + r;
            float v[4], mx = -3.0e38f;
#pragma unroll
            for (int nt = 0; nt < 4; ++nt) {
                int s = nt * 16 + nn;
                v[nt] = (s <= t) ? sc[nt][r] * 0.125f : -3.0e38f;
                mx = fmaxf(mx, v[nt]);
            }
            mx = fmaxf(mx, __shfl_xor(mx, 1)); mx = fmaxf(mx, __shfl_xor(mx, 2));
            mx = fmaxf(mx, __shfl_xor(mx, 4)); mx = fmaxf(mx, __shfl_xor(mx, 8));
            float e[4], ss = 0.f;
#pragma unroll
            for (int nt = 0; nt < 4; ++nt) { e[nt] = __expf(v[nt] - mx); ss += e[nt]; }
            ss += __shfl_xor(ss, 1); ss += __shfl_xor(ss, 2); ss += __shfl_xor(ss, 4); ss += __shfl_xor(ss, 8);
            float inv = 1.f / ss;
#pragma unroll
            for (int nt = 0; nt < 4; ++nt)
                sm[OP + t * ST + nt * 16 + nn] = f2bf(e[nt] * inv);
        }
        // PV: attn_h = P_h @ v_h  (N=8 valid; lanes n>=8 contribute zero B)
        f32x4 pv = zf;
#pragma unroll
        for (int ks = 0; ks < 2; ++ks) {
            short8 ap = *(const short8*)&sm[OP + (wv * 16 + nn) * ST + ks * 32 + quad * 8];
            short8 bvv = z8;
            if (nn < 8) bvv = *(const short8*)&sm[OV + (h * 8 + nn) * ST + ks * 32 + quad * 8];
            pv = mfma16(ap, bvv, pv);
        }
        if (nn < 8) {
#pragma unroll
            for (int r = 0; r < 4; ++r)
                sm[OH + (wv * 16 + quad * 4 + r) * ST + h * 8 + nn] = f2bf(pv[r]);  // a16
        }
    }

    // ---------- phase 4: Wo + residual + LN2 (a16 rows are own-wave; no barrier) ----------
    {
        f32x4 oa[4];
#pragma unroll
        for (int nt = 0; nt < 4; ++nt) oa[nt] = zf;
#pragma unroll
        for (int ks = 0; ks < 2; ++ks) {
            short8 aa = *(const short8*)&sm[OH + (wv * 16 + nn) * ST + ks * 32 + quad * 8];
#pragma unroll
            for (int nt = 0; nt < 4; ++nt) {
                short8 bf;
#pragma unroll
                for (int j = 0; j < 8; ++j)
                    bf[j] = f2bf(Wo[(ks * 32 + quad * 8 + j) * 64 + nt * 16 + nn]);
                oa[nt] = mfma16(aa, bf, oa[nt]);
            }
        }
#pragma unroll
        for (int nt = 0; nt < 4; ++nt) {
            float bov = bo[nt * 16 + nn];
#pragma unroll
            for (int r = 0; r < 4; ++r) xr[nt * 4 + r] += oa[nt][r] + bov;
        }
    }
    // LN2 in regs -> h2 into OH
#pragma unroll
    for (int nt = 0; nt < 4; ++nt) { gv[nt] = g2[nt * 16 + nn]; bv[nt] = be2[nt * 16 + nn]; }
#pragma unroll
    for (int r = 0; r < 4; ++r) {
        float s1 = 0.f, s2 = 0.f;
#pragma unroll
        for (int nt = 0; nt < 4; ++nt) { float v = xr[nt * 4 + r]; s1 += v; s2 += v * v; }
        s1 += __shfl_xor(s1, 1); s1 += __shfl_xor(s1, 2); s1 += __shfl_xor(s1, 4); s1 += __shfl_xor(s1, 8);
        s2 += __shfl_xor(s2, 1); s2 += __shfl_xor(s2, 2); s2 += __shfl_xor(s2, 4); s2 += __shfl_xor(s2, 8);
        float mu = s1 * 0.015625f;
        float rstd = rsqrtf(s2 * 0.015625f - mu * mu + 1e-5f);
        int t = wv * 16 + quad * 4 + r;
#pragma unroll
        for (int nt = 0; nt < 4; ++nt)
            sm[OH + t * ST + nt * 16 + nn] = f2bf((xr[nt * 4 + r] - mu) * rstd * gv[nt] + bv[nt]);
    }
    __syncthreads();

    // ---------- phase 5: FF in 4 K-chunks of 64 (u-chunk in OQ) ----------
    f32x4 fa[4];
#pragma unroll
    for (int nt = 0; nt < 4; ++nt) fa[nt] = zf;
#pragma unroll 1
    for (int c = 0; c < 4; ++c) {
        // FF1 chunk: wave w computes u cols (c*64 + w*16 + nn)
        f32x4 ua[4];
#pragma unroll
        for (int mt = 0; mt < 4; ++mt) ua[mt] = zf;
#pragma unroll
        for (int ks = 0; ks < 2; ++ks) {
            short8 bf;
#pragma unroll
            for (int j = 0; j < 8; ++j)
                bf[j] = f2bf(W1[(ks * 32 + quad * 8 + j) * 256 + c * 64 + wv * 16 + nn]);
#pragma unroll
            for (int mt = 0; mt < 4; ++mt) {
                short8 af = *(const short8*)&sm[OH + (mt * 16 + nn) * ST + ks * 32 + quad * 8];
                ua[mt] = mfma16(af, bf, ua[mt]);
            }
        }
        float b1v = b1[c * 64 + wv * 16 + nn];
        if (c > 0) __syncthreads();          // prior FF2 reads of OQ complete
#pragma unroll
        for (int mt = 0; mt < 4; ++mt)
#pragma unroll
            for (int r = 0; r < 4; ++r)
                sm[OQ + (mt * 16 + quad * 4 + r) * ST + wv * 16 + nn] = f2bf(fmaxf(ua[mt][r] + b1v, 0.f));
        __syncthreads();
        // FF2 partial: A = u-chunk rows 16w.., B = W2 chunk rows
#pragma unroll
        for (int ks = 0; ks < 2; ++ks) {
            short8 au = *(const short8*)&sm[OQ + (wv * 16 + nn) * ST + ks * 32 + quad * 8];
#pragma unroll
            for (int nt = 0; nt < 4; ++nt) {
                short8 bf;
#pragma unroll
                for (int j = 0; j < 8; ++j)
                    bf[j] = f2bf(W2[(c * 64 + ks * 32 + quad * 8 + j) * 64 + nt * 16 + nn]);
                fa[nt] = mfma16(au, bf, fa[nt]);
            }
        }
    }

    // ---------- phase 6: out = xr + ff + b2 ----------
    float* ob = out + (size_t)b * 4096;
#pragma unroll
    for (int nt = 0; nt < 4; ++nt) {
        float b2v = b2[nt * 16 + nn];
#pragma unroll
        for (int r = 0; r < 4; ++r)
            ob[(wv * 16 + quad * 4 + r) * 64 + nt * 16 + nn] = xr[nt * 4 + r] + fa[nt][r] + b2v;
    }
}

extern "C" void kernel_launch(void* const* d_in, const int* in_sizes, int n_in,
                              void* d_out, int out_size, void* d_ws, size_t ws_size,
                              hipStream_t stream) {
    const float* x   = (const float*)d_in[0];
    const float* Wq  = (const float*)d_in[1];
    const float* Wk  = (const float*)d_in[2];
    const float* Wv  = (const float*)d_in[3];
    const float* Wo  = (const float*)d_in[4];
    const float* bo  = (const float*)d_in[5];
    const float* W1  = (const float*)d_in[6];
    const float* b1  = (const float*)d_in[7];
    const float* W2  = (const float*)d_in[8];
    const float* b2  = (const float*)d_in[9];
    const float* g1  = (const float*)d_in[10];
    const float* be1 = (const float*)d_in[11];
    const float* g2  = (const float*)d_in[12];
    const float* be2 = (const float*)d_in[13];
    const int nb = in_sizes[0] / 4096;
    block_kernel<<<dim3(nb), dim3(256), 0, stream>>>(
        x, Wq, Wk, Wv, Wo, bo, W1, b1, W2, b2, g1, be1, g2, be2, (float*)d_out);
}

// Round 3
// 266.191 us; speedup vs baseline: 8.2583x; 1.2735x over previous
//
#include <hip/hip_runtime.h>

// Transformer block B=4096,T=64,C=64,H=8,hs=8,FF=256. fp32 in/out, bf16 MFMA inside.
// One batch per block, 256 threads (4 waves). Wave w owns output rows 16w..16w+15.
// All matmuls: __builtin_amdgcn_mfma_f32_16x16x32_bf16.
// C-frag layout: col=lane&15, row=quad*4+reg.  A[m=lane&15][k=quad*8+j], B[k=quad*8+j][n=lane&15].
// R3: weights pre-packed to bf16 MFMA B-fragment order in d_ws by a tiny kernel,
// so the main kernel loads each B-frag as one 16B/lane coalesced load (removes
// ~430 scalar loads + ~900 VALU cvt ops per lane per block).

typedef __attribute__((ext_vector_type(8))) short short8;
typedef __attribute__((ext_vector_type(4))) float f32x4;

#define ST 72            // bf16 row stride (144B, 16B-aligned)
#define OH  0            // h(LN1) [64][72]; reused as attn-concat a16; then h2(LN2)
#define OQ  4608         // q [64][72]; reused as u-chunk in FF
#define OKK 9216         // k [64][72]
#define OV  13824        // vT [64][72]  (vT[d][s])
#define OP  18432        // P (probs, per head) [64][72]
#define NSH 23040        // shorts = 46080 B -> 3 blocks/CU

__device__ __forceinline__ short f2bf(float f) {
    unsigned int u = __float_as_uint(f);
    u += 0x7fffu + ((u >> 16) & 1u);
    return (short)(u >> 16);
}

__device__ __forceinline__ f32x4 mfma16(short8 a, short8 b, f32x4 c) {
    return __builtin_amdgcn_mfma_f32_16x16x32_bf16(a, b, c, 0, 0, 0);
}

// ---- weight pre-pack: fp32 -> bf16, MFMA B-fragment order ----
// frag id (fid) layout in d_ws (short8 units, stride 64 lanes):
//   fid 0..23 : QKV   fid = tile*2+ks, tile 0..3=Wq,4..7=Wk,8..11=Wv, col=(tile&3)*16+nn
//   fid 24..31: Wo    fid-24 = nt*2+ks
//   fid 32..63: W1    fid-32 = c*8 + tile*2 + ks   (col = c*64+tile*16+nn, 256-wide)
//   fid 64..95: W2    fid-64 = c*8 + nt*2 + ks     (row = c*64+ks*32+quad*8+j)
__global__ __launch_bounds__(256) void prepack_kernel(
    const float* __restrict__ Wq, const float* __restrict__ Wk,
    const float* __restrict__ Wv, const float* __restrict__ Wo,
    const float* __restrict__ W1, const float* __restrict__ W2,
    short* __restrict__ ws)
{
    int gid = blockIdx.x * 256 + threadIdx.x;      // 24 blocks * 256 = 6144 = 96 fids * 64 lanes
    int lane = gid & 63;
    int fid  = gid >> 6;
    int quad = lane >> 4, nn = lane & 15;
    short8 o;
    if (fid < 24) {
        int tile = fid >> 1, ks = fid & 1;
        const float* Ws = (tile < 4) ? Wq : ((tile < 8) ? Wk : Wv);
        int col = (tile & 3) * 16 + nn;
#pragma unroll
        for (int j = 0; j < 8; ++j)
            o[j] = f2bf(Ws[(ks * 32 + quad * 8 + j) * 64 + col]);
    } else if (fid < 32) {
        int idx = fid - 24, nt = idx >> 1, ks = idx & 1;
#pragma unroll
        for (int j = 0; j < 8; ++j)
            o[j] = f2bf(Wo[(ks * 32 + quad * 8 + j) * 64 + nt * 16 + nn]);
    } else if (fid < 64) {
        int idx = fid - 32, c = idx >> 3, tile = (idx >> 1) & 3, ks = idx & 1;
#pragma unroll
        for (int j = 0; j < 8; ++j)
            o[j] = f2bf(W1[(ks * 32 + quad * 8 + j) * 256 + c * 64 + tile * 16 + nn]);
    } else {
        int idx = fid - 64, c = idx >> 3, nt = (idx >> 1) & 3, ks = idx & 1;
#pragma unroll
        for (int j = 0; j < 8; ++j)
            o[j] = f2bf(W2[(c * 64 + ks * 32 + quad * 8 + j) * 64 + nt * 16 + nn]);
    }
    *(short8*)(ws + (size_t)gid * 8) = o;
}

__global__ __launch_bounds__(256, 3) void block_kernel(
    const float* __restrict__ x,
    const float* __restrict__ bo,
    const float* __restrict__ b1,
    const float* __restrict__ b2,
    const float* __restrict__ g1, const float* __restrict__ be1,
    const float* __restrict__ g2, const float* __restrict__ be2,
    const short8* __restrict__ WB,
    float* __restrict__ out)
{
    __shared__ short sm[NSH];
    const int tid  = threadIdx.x;
    const int wv   = tid >> 6;
    const int lane = tid & 63;
    const int quad = lane >> 4;
    const int nn   = lane & 15;
    const int b    = blockIdx.x;
    const float* xb = x + (size_t)b * 4096;

    // ---------- phase 1: load x (regs, C-layout), LN1 -> h ----------
    float xr[16];                       // xr[nt*4+r] = x[t(r)][col(nt)]
    float gv[4], bv[4];
#pragma unroll
    for (int nt = 0; nt < 4; ++nt) { gv[nt] = g1[nt * 16 + nn]; bv[nt] = be1[nt * 16 + nn]; }
#pragma unroll
    for (int nt = 0; nt < 4; ++nt)
#pragma unroll
        for (int r = 0; r < 4; ++r)
            xr[nt * 4 + r] = xb[(wv * 16 + quad * 4 + r) * 64 + nt * 16 + nn];
#pragma unroll
    for (int r = 0; r < 4; ++r) {
        float s1 = 0.f, s2 = 0.f;
#pragma unroll
        for (int nt = 0; nt < 4; ++nt) { float v = xr[nt * 4 + r]; s1 += v; s2 += v * v; }
        s1 += __shfl_xor(s1, 1); s1 += __shfl_xor(s1, 2); s1 += __shfl_xor(s1, 4); s1 += __shfl_xor(s1, 8);
        s2 += __shfl_xor(s2, 1); s2 += __shfl_xor(s2, 2); s2 += __shfl_xor(s2, 4); s2 += __shfl_xor(s2, 8);
        float mu = s1 * 0.015625f;
        float rstd = rsqrtf(s2 * 0.015625f - mu * mu + 1e-5f);
        int t = wv * 16 + quad * 4 + r;
#pragma unroll
        for (int nt = 0; nt < 4; ++nt)
            sm[OH + t * ST + nt * 16 + nn] = f2bf((xr[nt * 4 + r] - mu) * rstd * gv[nt] + bv[nt]);
    }
    __syncthreads();

    // ---------- phase 2: QKV = h @ [Wq|Wk|Wv]  (wave w: col tiles 3w..3w+2) ----------
    {
        f32x4 acc[3][4];
#pragma unroll
        for (int a = 0; a < 3; ++a)
#pragma unroll
            for (int m = 0; m < 4; ++m) acc[a][m] = (f32x4){0.f, 0.f, 0.f, 0.f};
#pragma unroll
        for (int ks = 0; ks < 2; ++ks) {
            short8 af[4];
#pragma unroll
            for (int mt = 0; mt < 4; ++mt)
                af[mt] = *(const short8*)&sm[OH + (mt * 16 + nn) * ST + ks * 32 + quad * 8];
#pragma unroll
            for (int ntl = 0; ntl < 3; ++ntl) {
                int tile = wv * 3 + ntl;
                short8 bf = WB[(size_t)(tile * 2 + ks) * 64 + lane];
#pragma unroll
                for (int mt = 0; mt < 4; ++mt)
                    acc[ntl][mt] = mfma16(af[mt], bf, acc[ntl][mt]);
            }
        }
#pragma unroll
        for (int ntl = 0; ntl < 3; ++ntl) {
            int tile = wv * 3 + ntl;
#pragma unroll
            for (int mt = 0; mt < 4; ++mt)
#pragma unroll
                for (int r = 0; r < 4; ++r) {
                    int row = mt * 16 + quad * 4 + r;
                    short v = f2bf(acc[ntl][mt][r]);
                    if (tile < 4)      sm[OQ  + row * ST + tile * 16 + nn] = v;
                    else if (tile < 8) sm[OKK + row * ST + (tile - 4) * 16 + nn] = v;
                    else               sm[OV  + ((tile - 8) * 16 + nn) * ST + row] = v;  // vT[d][s]
                }
        }
    }
    __syncthreads();

    // ---------- phase 3: attention (no barriers; wave w owns rows 16w..16w+15) ----------
    const f32x4 zf = {0.f, 0.f, 0.f, 0.f};
    const short8 z8 = {0, 0, 0, 0, 0, 0, 0, 0};
#pragma unroll 1
    for (int h = 0; h < 8; ++h) {
        // scores: S = q_h @ k_h^T  (K=8 zero-padded to 32; quad 0 carries data)
        short8 aq = z8;
        if (quad == 0) aq = *(const short8*)&sm[OQ + (wv * 16 + nn) * ST + h * 8];
        f32x4 sc[4];
#pragma unroll
        for (int nt = 0; nt < 4; ++nt) {
            short8 bk = z8;
            if (quad == 0) bk = *(const short8*)&sm[OKK + (nt * 16 + nn) * ST + h * 8];
            sc[nt] = mfma16(aq, bk, zf);
        }
        // softmax rows t = wv*16 + quad*4 + r (row lives in this quad's 16 lanes)
#pragma unroll
        for (int r = 0; r < 4; ++r) {
            int t = wv * 16 + quad * 4 + r;
            float v[4], mx = -3.0e38f;
#pragma unroll
            for (int nt = 0; nt < 4; ++nt) {
                int s = nt * 16 + nn;
                v[nt] = (s <= t) ? sc[nt][r] * 0.125f : -3.0e38f;
                mx = fmaxf(mx, v[nt]);
            }
            mx = fmaxf(mx, __shfl_xor(mx, 1)); mx = fmaxf(mx, __shfl_xor(mx, 2));
            mx = fmaxf(mx, __shfl_xor(mx, 4)); mx = fmaxf(mx, __shfl_xor(mx, 8));
            float e[4], ss = 0.f;
#pragma unroll
            for (int nt = 0; nt < 4; ++nt) { e[nt] = __expf(v[nt] - mx); ss += e[nt]; }
            ss += __shfl_xor(ss, 1); ss += __shfl_xor(ss, 2); ss += __shfl_xor(ss, 4); ss += __shfl_xor(ss, 8);
            float inv = 1.f / ss;
#pragma unroll
            for (int nt = 0; nt < 4; ++nt)
                sm[OP + t * ST + nt * 16 + nn] = f2bf(e[nt] * inv);
        }
        // PV: attn_h = P_h @ v_h  (N=8 valid; lanes n>=8 contribute zero B)
        f32x4 pv = zf;
#pragma unroll
        for (int ks = 0; ks < 2; ++ks) {
            short8 ap = *(const short8*)&sm[OP + (wv * 16 + nn) * ST + ks * 32 + quad * 8];
            short8 bvv = z8;
            if (nn < 8) bvv = *(const short8*)&sm[OV + (h * 8 + nn) * ST + ks * 32 + quad * 8];
            pv = mfma16(ap, bvv, pv);
        }
        if (nn < 8) {
#pragma unroll
            for (int r = 0; r < 4; ++r)
                sm[OH + (wv * 16 + quad * 4 + r) * ST + h * 8 + nn] = f2bf(pv[r]);  // a16
        }
    }

    // ---------- phase 4: Wo + residual + LN2 (a16 rows are own-wave; no barrier) ----------
    {
        f32x4 oa[4];
#pragma unroll
        for (int nt = 0; nt < 4; ++nt) oa[nt] = zf;
#pragma unroll
        for (int ks = 0; ks < 2; ++ks) {
            short8 aa = *(const short8*)&sm[OH + (wv * 16 + nn) * ST + ks * 32 + quad * 8];
#pragma unroll
            for (int nt = 0; nt < 4; ++nt) {
                short8 bf = WB[(size_t)(24 + nt * 2 + ks) * 64 + lane];
                oa[nt] = mfma16(aa, bf, oa[nt]);
            }
        }
#pragma unroll
        for (int nt = 0; nt < 4; ++nt) {
            float bov = bo[nt * 16 + nn];
#pragma unroll
            for (int r = 0; r < 4; ++r) xr[nt * 4 + r] += oa[nt][r] + bov;
        }
    }
    // LN2 in regs -> h2 into OH
#pragma unroll
    for (int nt = 0; nt < 4; ++nt) { gv[nt] = g2[nt * 16 + nn]; bv[nt] = be2[nt * 16 + nn]; }
#pragma unroll
    for (int r = 0; r < 4; ++r) {
        float s1 = 0.f, s2 = 0.f;
#pragma unroll
        for (int nt = 0; nt < 4; ++nt) { float v = xr[nt * 4 + r]; s1 += v; s2 += v * v; }
        s1 += __shfl_xor(s1, 1); s1 += __shfl_xor(s1, 2); s1 += __shfl_xor(s1, 4); s1 += __shfl_xor(s1, 8);
        s2 += __shfl_xor(s2, 1); s2 += __shfl_xor(s2, 2); s2 += __shfl_xor(s2, 4); s2 += __shfl_xor(s2, 8);
        float mu = s1 * 0.015625f;
        float rstd = rsqrtf(s2 * 0.015625f - mu * mu + 1e-5f);
        int t = wv * 16 + quad * 4 + r;
#pragma unroll
        for (int nt = 0; nt < 4; ++nt)
            sm[OH + t * ST + nt * 16 + nn] = f2bf((xr[nt * 4 + r] - mu) * rstd * gv[nt] + bv[nt]);
    }
    __syncthreads();

    // ---------- phase 5: FF in 4 K-chunks of 64 (u-chunk in OQ) ----------
    f32x4 fa[4];
#pragma unroll
    for (int nt = 0; nt < 4; ++nt) fa[nt] = zf;
#pragma unroll 1
    for (int c = 0; c < 4; ++c) {
        // FF1 chunk: wave w computes u cols (c*64 + w*16 + nn)
        f32x4 ua[4];
#pragma unroll
        for (int mt = 0; mt < 4; ++mt) ua[mt] = zf;
#pragma unroll
        for (int ks = 0; ks < 2; ++ks) {
            short8 bf = WB[(size_t)(32 + c * 8 + wv * 2 + ks) * 64 + lane];
#pragma unroll
            for (int mt = 0; mt < 4; ++mt) {
                short8 af = *(const short8*)&sm[OH + (mt * 16 + nn) * ST + ks * 32 + quad * 8];
                ua[mt] = mfma16(af, bf, ua[mt]);
            }
        }
        float b1v = b1[c * 64 + wv * 16 + nn];
        if (c > 0) __syncthreads();          // prior FF2 reads of OQ complete
#pragma unroll
        for (int mt = 0; mt < 4; ++mt)
#pragma unroll
            for (int r = 0; r < 4; ++r)
                sm[OQ + (mt * 16 + quad * 4 + r) * ST + wv * 16 + nn] = f2bf(fmaxf(ua[mt][r] + b1v, 0.f));
        __syncthreads();
        // FF2 partial: A = u-chunk rows 16w.., B = W2 chunk rows
#pragma unroll
        for (int ks = 0; ks < 2; ++ks) {
            short8 au = *(const short8*)&sm[OQ + (wv * 16 + nn) * ST + ks * 32 + quad * 8];
#pragma unroll
            for (int nt = 0; nt < 4; ++nt) {
                short8 bf = WB[(size_t)(64 + c * 8 + nt * 2 + ks) * 64 + lane];
                fa[nt] = mfma16(au, bf, fa[nt]);
            }
        }
    }

    // ---------- phase 6: out = xr + ff + b2 ----------
    float* ob = out + (size_t)b * 4096;
#pragma unroll
    for (int nt = 0; nt < 4; ++nt) {
        float b2v = b2[nt * 16 + nn];
#pragma unroll
        for (int r = 0; r < 4; ++r)
            ob[(wv * 16 + quad * 4 + r) * 64 + nt * 16 + nn] = xr[nt * 4 + r] + fa[nt][r] + b2v;
    }
}

extern "C" void kernel_launch(void* const* d_in, const int* in_sizes, int n_in,
                              void* d_out, int out_size, void* d_ws, size_t ws_size,
                              hipStream_t stream) {
    const float* x   = (const float*)d_in[0];
    const float* Wq  = (const float*)d_in[1];
    const float* Wk  = (const float*)d_in[2];
    const float* Wv  = (const float*)d_in[3];
    const float* Wo  = (const float*)d_in[4];
    const float* bo  = (const float*)d_in[5];
    const float* W1  = (const float*)d_in[6];
    const float* b1  = (const float*)d_in[7];
    const float* W2  = (const float*)d_in[8];
    const float* b2  = (const float*)d_in[9];
    const float* g1  = (const float*)d_in[10];
    const float* be1 = (const float*)d_in[11];
    const float* g2  = (const float*)d_in[12];
    const float* be2 = (const float*)d_in[13];
    short* ws = (short*)d_ws;
    prepack_kernel<<<dim3(24), dim3(256), 0, stream>>>(Wq, Wk, Wv, Wo, W1, W2, ws);
    const int nb = in_sizes[0] / 4096;
    block_kernel<<<dim3(nb), dim3(256), 0, stream>>>(
        x, bo, b1, b2, g1, be1, g2, be2, (const short8*)ws, (float*)d_out);
}

// Round 4
// 206.431 us; speedup vs baseline: 10.6490x; 1.2895x over previous
//
#include <hip/hip_runtime.h>
#include <hip/hip_bf16.h>

// Transformer block B=4096,T=64,C=64,H=8,hs=8,FF=256. fp32 in/out, bf16 MFMA.
// One batch/block, 4 waves; wave w owns rows t in [16w,16w+16).
// mfma_f32_16x16x32_bf16: C col=lane&15,row=quad*4+reg; A[m=lane&15][k=quad*8+j];
// B[k=quad*8+j][n=lane&15]. A-frag and B-frag share the same lane->W[k][col] map,
// so one packed weight serves as A (swapped product) or B (direct product).
// R4: swapped-orientation q/k/FF1 (contiguous b64 epilogues), S^T attention with
// exp-only softmax (scores bounded; scale*log2e folded into Wq prepack),
// normalization deferred via ones-row in the PV A-operand, 3 barriers total.

typedef __attribute__((ext_vector_type(8))) short short8;
typedef __attribute__((ext_vector_type(4))) float f32x4;

#if __has_builtin(__builtin_amdgcn_exp2f)
#define EXP2F(x) __builtin_amdgcn_exp2f(x)
#else
#define EXP2F(x) __expf((x) * 0.69314718056f)
#endif
#if __has_builtin(__builtin_amdgcn_rcpf)
#define RCPF(x) __builtin_amdgcn_rcpf(x)
#else
#define RCPF(x) (1.0f / (x))
#endif

#define ST  72           // bf16 row stride (144 B)
#define STU 264          // u row stride (528 B)
#define OH  0            // h(LN1) [64][ST]; later attn-concat a16
#define OQ  4608         // q [64][ST]; later h2(LN2)
#define OKK 9216         // k [64][ST]
#define OV  13824        // vT rows 0..63; row 64 = ones, row 65 = zeros
#define OP  18576        // P (unnormalized probs) [64][ST]
#define OU  9216         // u [64][STU] (overlays k,vT,P after attention)
#define NSH 26112        // shorts = 52224 B -> 3 blocks/CU

__device__ __forceinline__ short f2bf(float f) {
    unsigned int u = __float_as_uint(f);
    u += 0x7fffu + ((u >> 16) & 1u);
    return (short)(u >> 16);
}
__device__ __forceinline__ unsigned pk2(float a, float b) {
    float2 t; t.x = a; t.y = b;
    __hip_bfloat162 h = __float22bfloat162_rn(t);
    unsigned u; __builtin_memcpy(&u, &h, 4); return u;
}
__device__ __forceinline__ f32x4 mfma16(short8 a, short8 b, f32x4 c) {
    return __builtin_amdgcn_mfma_f32_16x16x32_bf16(a, b, c, 0, 0, 0);
}

// ---- weight pre-pack: fp32 -> bf16 frag order (same map as R3; Wq pre-scaled) ----
// fid 0..23: QKV (tile*2+ks; 0..3 Wq,4..7 Wk,8..11 Wv); 24..31: Wo; 32..63: W1; 64..95: W2
__global__ __launch_bounds__(256) void prepack_kernel(
    const float* __restrict__ Wq, const float* __restrict__ Wk,
    const float* __restrict__ Wv, const float* __restrict__ Wo,
    const float* __restrict__ W1, const float* __restrict__ W2,
    short* __restrict__ ws)
{
    int gid = blockIdx.x * 256 + threadIdx.x;      // 24 blocks -> 96 fids * 64 lanes
    int lane = gid & 63;
    int fid  = gid >> 6;
    int quad = lane >> 4, nn = lane & 15;
    short8 o;
    if (fid < 24) {
        int tile = fid >> 1, ks = fid & 1;
        const float* Ws = (tile < 4) ? Wq : ((tile < 8) ? Wk : Wv);
        float scale = (tile < 4) ? 0.18033688011f : 1.0f;   // 1/8 * log2(e) folded into q
        int col = (tile & 3) * 16 + nn;
#pragma unroll
        for (int j = 0; j < 8; ++j)
            o[j] = f2bf(Ws[(ks * 32 + quad * 8 + j) * 64 + col] * scale);
    } else if (fid < 32) {
        int idx = fid - 24, nt = idx >> 1, ks = idx & 1;
#pragma unroll
        for (int j = 0; j < 8; ++j)
            o[j] = f2bf(Wo[(ks * 32 + quad * 8 + j) * 64 + nt * 16 + nn]);
    } else if (fid < 64) {
        int idx = fid - 32, c = idx >> 3, tile = (idx >> 1) & 3, ks = idx & 1;
#pragma unroll
        for (int j = 0; j < 8; ++j)
            o[j] = f2bf(W1[(ks * 32 + quad * 8 + j) * 256 + c * 64 + tile * 16 + nn]);
    } else {
        int idx = fid - 64, c = idx >> 3, nt = (idx >> 1) & 3, ks = idx & 1;
#pragma unroll
        for (int j = 0; j < 8; ++j)
            o[j] = f2bf(W2[(c * 64 + ks * 32 + quad * 8 + j) * 64 + nt * 16 + nn]);
    }
    *(short8*)(ws + (size_t)gid * 8) = o;
}

__global__ __launch_bounds__(256, 3) void block_kernel(
    const float* __restrict__ x,
    const float* __restrict__ bo,
    const float* __restrict__ b1,
    const float* __restrict__ b2,
    const float* __restrict__ g1, const float* __restrict__ be1,
    const float* __restrict__ g2, const float* __restrict__ be2,
    const short8* __restrict__ WB,
    float* __restrict__ out)
{
    __shared__ short sm[NSH];
    const int tid  = threadIdx.x;
    const int wv   = tid >> 6;
    const int lane = tid & 63;
    const int quad = lane >> 4;
    const int nn   = lane & 15;
    const int t_my = wv * 16 + nn;        // column-owned row index for swapped products
    const int b    = blockIdx.x;
    const float* xb = x + (size_t)b * 4096;
    const f32x4 zf = {0.f, 0.f, 0.f, 0.f};
    const short8 z8 = {0, 0, 0, 0, 0, 0, 0, 0};

    // ---------- phase 1: x -> regs (C-layout), LN1 -> h; init ones/zero rows ----------
    if (tid < 144) sm[OV + 64 * ST + tid] = (tid < ST) ? (short)0x3F80 : (short)0;
    float xr[16];                          // xr[nt*4+r] = x[16wv+quad*4+r][nt*16+nn]
    float gv[4], bv[4];
#pragma unroll
    for (int nt = 0; nt < 4; ++nt) { gv[nt] = g1[nt * 16 + nn]; bv[nt] = be1[nt * 16 + nn]; }
#pragma unroll
    for (int nt = 0; nt < 4; ++nt)
#pragma unroll
        for (int r = 0; r < 4; ++r)
            xr[nt * 4 + r] = xb[(wv * 16 + quad * 4 + r) * 64 + nt * 16 + nn];
#pragma unroll
    for (int r = 0; r < 4; ++r) {
        float s1 = 0.f, s2 = 0.f;
#pragma unroll
        for (int nt = 0; nt < 4; ++nt) { float v = xr[nt * 4 + r]; s1 += v; s2 += v * v; }
        s1 += __shfl_xor(s1, 1); s1 += __shfl_xor(s1, 2); s1 += __shfl_xor(s1, 4); s1 += __shfl_xor(s1, 8);
        s2 += __shfl_xor(s2, 1); s2 += __shfl_xor(s2, 2); s2 += __shfl_xor(s2, 4); s2 += __shfl_xor(s2, 8);
        float mu = s1 * 0.015625f;
        float rstd = rsqrtf(s2 * 0.015625f - mu * mu + 1e-5f);
        int base = OH + (wv * 16 + quad * 4 + r) * ST + nn;
        float v0 = (xr[0 * 4 + r] - mu) * rstd * gv[0] + bv[0];
        float v1 = (xr[1 * 4 + r] - mu) * rstd * gv[1] + bv[1];
        float v2 = (xr[2 * 4 + r] - mu) * rstd * gv[2] + bv[2];
        float v3 = (xr[3 * 4 + r] - mu) * rstd * gv[3] + bv[3];
        unsigned p01 = pk2(v0, v1), p23 = pk2(v2, v3);
        sm[base]      = (short)(p01 & 0xffff);
        sm[base + 16] = (short)(p01 >> 16);
        sm[base + 32] = (short)(p23 & 0xffff);
        sm[base + 48] = (short)(p23 >> 16);
    }
    // no barrier: phase 2 reads only own h rows

    // ---------- phase 2: q,k swapped (W^T as A, h as B); v direct -> vT ----------
    {
        short8 hf0 = *(const short8*)&sm[OH + t_my * ST + quad * 8];
        short8 hf1 = *(const short8*)&sm[OH + t_my * ST + 32 + quad * 8];
#pragma unroll
        for (int jt = 0; jt < 4; ++jt) {           // q: C[j][t] -> store q[t][j]
            f32x4 a = mfma16(WB[(size_t)(jt * 2 + 0) * 64 + lane], hf0, zf);
            a = mfma16(WB[(size_t)(jt * 2 + 1) * 64 + lane], hf1, a);
            uint2 w; w.x = pk2(a[0], a[1]); w.y = pk2(a[2], a[3]);
            *(uint2*)&sm[OQ + t_my * ST + jt * 16 + quad * 4] = w;
        }
#pragma unroll
        for (int jt = 0; jt < 4; ++jt) {           // k
            f32x4 a = mfma16(WB[(size_t)((4 + jt) * 2 + 0) * 64 + lane], hf0, zf);
            a = mfma16(WB[(size_t)((4 + jt) * 2 + 1) * 64 + lane], hf1, a);
            uint2 w; w.x = pk2(a[0], a[1]); w.y = pk2(a[2], a[3]);
            *(uint2*)&sm[OKK + t_my * ST + jt * 16 + quad * 4] = w;
        }
#pragma unroll
        for (int dt = 0; dt < 4; ++dt) {           // v direct: C[t][d] -> store vT[d][t]
            f32x4 a = mfma16(hf0, WB[(size_t)((8 + dt) * 2 + 0) * 64 + lane], zf);
            a = mfma16(hf1, WB[(size_t)((8 + dt) * 2 + 1) * 64 + lane], a);
            uint2 w; w.x = pk2(a[0], a[1]); w.y = pk2(a[2], a[3]);
            *(uint2*)&sm[OV + (dt * 16 + nn) * ST + wv * 16 + quad * 4] = w;
        }
    }
    __syncthreads();   // B1: k, vT, ones-rows read across waves in attention

    // ---------- phase 3: attention, S^T scheme, zero barriers ----------
    const bool keep0 = (quad * 4 + 0) <= nn, keep1 = (quad * 4 + 1) <= nn;
    const bool keep2 = (quad * 4 + 2) <= nn, keep3 = (quad * 4 + 3) <= nn;
    const int arow_base = (nn < 8) ? nn : ((nn == 8) ? 64 : 65);   // ones row 64, zero row 65
    const int arow_step = (nn < 8) ? 8 : 0;
    const int nks = (wv < 2) ? 1 : 2;      // PV K-range: s < nks*32 covers all unmasked s
    const int zhi = nks * 2;               // P tiles that must be zeroed if not computed
#pragma unroll 1
    for (int h = 0; h < 8; ++h) {
        short8 bq = z8;
        if (quad == 0) bq = *(const short8*)&sm[OQ + t_my * ST + h * 8];
        for (int mt = 0; mt <= wv; ++mt) {         // causal: s-tiles above wv are all-masked
            short8 ak = z8;
            if (quad == 0) ak = *(const short8*)&sm[OKK + (mt * 16 + nn) * ST + h * 8];
            f32x4 s = mfma16(ak, bq, zf);          // S^T[s][t], rows s, col t=t_my
            float e0 = EXP2F(s[0]), e1 = EXP2F(s[1]), e2 = EXP2F(s[2]), e3 = EXP2F(s[3]);
            if (mt == wv) {                        // diagonal tile: apply causal mask
                e0 = keep0 ? e0 : 0.f; e1 = keep1 ? e1 : 0.f;
                e2 = keep2 ? e2 : 0.f; e3 = keep3 ? e3 : 0.f;
            }
            uint2 w; w.x = pk2(e0, e1); w.y = pk2(e2, e3);
            *(uint2*)&sm[OP + t_my * ST + mt * 16 + quad * 4] = w;
        }
        for (int mt = wv + 1; mt < zhi; ++mt) {    // zero tiles PV will read
            uint2 w; w.x = 0u; w.y = 0u;
            *(uint2*)&sm[OP + t_my * ST + mt * 16 + quad * 4] = w;
        }
        // PV: A = vT rows (d<8) + ones row (m=8) -> C row 8 = row-sum (denominator)
        const int arow = arow_base + h * arow_step;
        f32x4 pv = zf;
        for (int ks = 0; ks < nks; ++ks) {
            short8 av = *(const short8*)&sm[OV + arow * ST + ks * 32 + quad * 8];
            short8 bp = *(const short8*)&sm[OP + t_my * ST + ks * 32 + quad * 8];
            pv = mfma16(av, bp, pv);
        }
        float denom = __shfl(pv[0], 32 + nn);      // row m=8 lives at quad 2, reg 0
        float rd = RCPF(denom);
        if (quad < 2) {                            // valid d = quad*4+r in 0..7
            uint2 w; w.x = pk2(pv[0] * rd, pv[1] * rd); w.y = pk2(pv[2] * rd, pv[3] * rd);
            *(uint2*)&sm[OH + t_my * ST + h * 8 + quad * 4] = w;   // a16[t][h*8+d]
        }
    }

    // ---------- phase 4: Wo + residual (direct; matches xr layout) + LN2 ----------
    {
        short8 aa0 = *(const short8*)&sm[OH + t_my * ST + quad * 8];
        short8 aa1 = *(const short8*)&sm[OH + t_my * ST + 32 + quad * 8];
#pragma unroll
        for (int nt = 0; nt < 4; ++nt) {
            f32x4 oa = mfma16(aa0, WB[(size_t)(24 + nt * 2 + 0) * 64 + lane], zf);
            oa = mfma16(aa1, WB[(size_t)(24 + nt * 2 + 1) * 64 + lane], oa);
            float bov = bo[nt * 16 + nn];
#pragma unroll
            for (int r = 0; r < 4; ++r) xr[nt * 4 + r] += oa[r] + bov;
        }
    }
#pragma unroll
    for (int nt = 0; nt < 4; ++nt) { gv[nt] = g2[nt * 16 + nn]; bv[nt] = be2[nt * 16 + nn]; }
#pragma unroll
    for (int r = 0; r < 4; ++r) {
        float s1 = 0.f, s2 = 0.f;
#pragma unroll
        for (int nt = 0; nt < 4; ++nt) { float v = xr[nt * 4 + r]; s1 += v; s2 += v * v; }
        s1 += __shfl_xor(s1, 1); s1 += __shfl_xor(s1, 2); s1 += __shfl_xor(s1, 4); s1 += __shfl_xor(s1, 8);
        s2 += __shfl_xor(s2, 1); s2 += __shfl_xor(s2, 2); s2 += __shfl_xor(s2, 4); s2 += __shfl_xor(s2, 8);
        float mu = s1 * 0.015625f;
        float rstd = rsqrtf(s2 * 0.015625f - mu * mu + 1e-5f);
        int base = OQ + (wv * 16 + quad * 4 + r) * ST + nn;   // h2 over q
        float v0 = (xr[0 * 4 + r] - mu) * rstd * gv[0] + bv[0];
        float v1 = (xr[1 * 4 + r] - mu) * rstd * gv[1] + bv[1];
        float v2 = (xr[2 * 4 + r] - mu) * rstd * gv[2] + bv[2];
        float v3 = (xr[3 * 4 + r] - mu) * rstd * gv[3] + bv[3];
        unsigned p01 = pk2(v0, v1), p23 = pk2(v2, v3);
        sm[base]      = (short)(p01 & 0xffff);
        sm[base + 16] = (short)(p01 >> 16);
        sm[base + 32] = (short)(p23 & 0xffff);
        sm[base + 48] = (short)(p23 >> 16);
    }

    // ---------- phase 5: FF1 swapped (one shot), FF2 direct ----------
    short8 h2f0 = *(const short8*)&sm[OQ + t_my * ST + quad * 8];
    short8 h2f1 = *(const short8*)&sm[OQ + t_my * ST + 32 + quad * 8];
    __syncthreads();   // B2: u overlays k/vT/P; all waves must be done with attention reads
#pragma unroll
    for (int c = 0; c < 4; ++c)
#pragma unroll
        for (int tile = 0; tile < 4; ++tile) {
            int fid = 32 + c * 8 + tile * 2;
            f32x4 u = mfma16(WB[(size_t)fid * 64 + lane], h2f0, zf);
            u = mfma16(WB[(size_t)(fid + 1) * 64 + lane], h2f1, u);
            const float4 bb = *(const float4*)&b1[c * 64 + tile * 16 + quad * 4];
            float u0 = fmaxf(u[0] + bb.x, 0.f), u1 = fmaxf(u[1] + bb.y, 0.f);
            float u2 = fmaxf(u[2] + bb.z, 0.f), u3 = fmaxf(u[3] + bb.w, 0.f);
            uint2 w; w.x = pk2(u0, u1); w.y = pk2(u2, u3);
            *(uint2*)&sm[OU + t_my * STU + c * 64 + tile * 16 + quad * 4] = w;
        }
    // FF2 reads only own u row (written by this wave) -> no barrier
    short8 uf[8];
#pragma unroll
    for (int ks = 0; ks < 8; ++ks)
        uf[ks] = *(const short8*)&sm[OU + t_my * STU + ks * 32 + quad * 8];
    f32x4 fa[4];
#pragma unroll
    for (int nt = 0; nt < 4; ++nt) fa[nt] = zf;
#pragma unroll
    for (int nt = 0; nt < 4; ++nt)
#pragma unroll
        for (int ks = 0; ks < 8; ++ks)
            fa[nt] = mfma16(uf[ks], WB[(size_t)(64 + (ks >> 1) * 8 + nt * 2 + (ks & 1)) * 64 + lane], fa[nt]);

    // ---------- phase 6: out = xr + ff + b2 ----------
    float* ob = out + (size_t)b * 4096;
#pragma unroll
    for (int nt = 0; nt < 4; ++nt) {
        float b2v = b2[nt * 16 + nn];
#pragma unroll
        for (int r = 0; r < 4; ++r)
            ob[(wv * 16 + quad * 4 + r) * 64 + nt * 16 + nn] = xr[nt * 4 + r] + fa[nt][r] + b2v;
    }
}

extern "C" void kernel_launch(void* const* d_in, const int* in_sizes, int n_in,
                              void* d_out, int out_size, void* d_ws, size_t ws_size,
                              hipStream_t stream) {
    const float* x   = (const float*)d_in[0];
    const float* Wq  = (const float*)d_in[1];
    const float* Wk  = (const float*)d_in[2];
    const float* Wv  = (const float*)d_in[3];
    const float* Wo  = (const float*)d_in[4];
    const float* bo  = (const float*)d_in[5];
    const float* W1  = (const float*)d_in[6];
    const float* b1  = (const float*)d_in[7];
    const float* W2  = (const float*)d_in[8];
    const float* b2  = (const float*)d_in[9];
    const float* g1  = (const float*)d_in[10];
    const float* be1 = (const float*)d_in[11];
    const float* g2  = (const float*)d_in[12];
    const float* be2 = (const float*)d_in[13];
    short* ws = (short*)d_ws;
    prepack_kernel<<<dim3(24), dim3(256), 0, stream>>>(Wq, Wk, Wv, Wo, W1, W2, ws);
    const int nb = in_sizes[0] / 4096;
    block_kernel<<<dim3(nb), dim3(256), 0, stream>>>(
        x, bo, b1, b2, g1, be1, g2, be2, (const short8*)ws, (float*)d_out);
}

// Round 5
// 202.230 us; speedup vs baseline: 10.8702x; 1.0208x over previous
//
#include <hip/hip_runtime.h>
#include <hip/hip_bf16.h>

// Transformer block B=4096,T=64,C=64,H=8,hs=8,FF=256. fp32 in/out, bf16 MFMA.
// One batch/block, 4 waves; wave w owns rows t in [16w,16w+16).
// mfma_f32_16x16x32_bf16: C col=lane&15,row=quad*4+reg; A[m=lane&15][k=quad*8+j];
// B[k=quad*8+j][n=lane&15]. A-frag and B-frag share the same lane->W[k][col] map.
// R5: q kept in registers (per-head B-frag via 4 wave-uniform shfls; A-side zeros
// kill B-side garbage in quads 1-3), h2 reuses the dead P region, FF in 2 K-chunks
// (u rows wave-private => no extra barrier), zero-row dropped. LDS 52->37 KB =>
// 4 blocks/CU. Barriers: 2.

typedef __attribute__((ext_vector_type(8))) short short8;
typedef __attribute__((ext_vector_type(4))) float f32x4;

#if __has_builtin(__builtin_amdgcn_exp2f)
#define EXP2F(x) __builtin_amdgcn_exp2f(x)
#else
#define EXP2F(x) __expf((x) * 0.69314718056f)
#endif
#if __has_builtin(__builtin_amdgcn_rcpf)
#define RCPF(x) __builtin_amdgcn_rcpf(x)
#else
#define RCPF(x) (1.0f / (x))
#endif

#define ST  72           // bf16 row stride (144 B)
#define STU 136          // u chunk row stride (272 B)
#define OH  0            // h(LN1) [64][ST]; later attn-concat a16
#define OKK 4608         // k [64][ST]
#define OV  9216         // vT rows 0..63 + ones row 64  (65 x ST)
#define OP  13896        // P (unnormalized probs) [64][ST]; later h2 (C-layout)
#define OU  4608         // u chunk [64][STU] (overlays k,vT after attention)
#define NSH 18504        // shorts = 37008 B -> 4 blocks/CU

__device__ __forceinline__ short f2bf(float f) {
    unsigned int u = __float_as_uint(f);
    u += 0x7fffu + ((u >> 16) & 1u);
    return (short)(u >> 16);
}
__device__ __forceinline__ unsigned pk2(float a, float b) {
    float2 t; t.x = a; t.y = b;
    __hip_bfloat162 h = __float22bfloat162_rn(t);
    unsigned u; __builtin_memcpy(&u, &h, 4); return u;
}
__device__ __forceinline__ f32x4 mfma16(short8 a, short8 b, f32x4 c) {
    return __builtin_amdgcn_mfma_f32_16x16x32_bf16(a, b, c, 0, 0, 0);
}

// ---- weight pre-pack: fp32 -> bf16 frag order (Wq pre-scaled by 1/8*log2e) ----
// fid 0..23: QKV (tile*2+ks; 0..3 Wq,4..7 Wk,8..11 Wv); 24..31: Wo; 32..63: W1; 64..95: W2
__global__ __launch_bounds__(64) void prepack_kernel(
    const float* __restrict__ Wq, const float* __restrict__ Wk,
    const float* __restrict__ Wv, const float* __restrict__ Wo,
    const float* __restrict__ W1, const float* __restrict__ W2,
    short* __restrict__ ws)
{
    int gid = blockIdx.x * 64 + threadIdx.x;       // 96 blocks * 64 = 96 fids * 64 lanes
    int lane = gid & 63;
    int fid  = gid >> 6;
    int quad = lane >> 4, nn = lane & 15;
    short8 o;
    if (fid < 24) {
        int tile = fid >> 1, ks = fid & 1;
        const float* Ws = (tile < 4) ? Wq : ((tile < 8) ? Wk : Wv);
        float scale = (tile < 4) ? 0.18033688011f : 1.0f;   // 1/8 * log2(e) folded into q
        int col = (tile & 3) * 16 + nn;
#pragma unroll
        for (int j = 0; j < 8; ++j)
            o[j] = f2bf(Ws[(ks * 32 + quad * 8 + j) * 64 + col] * scale);
    } else if (fid < 32) {
        int idx = fid - 24, nt = idx >> 1, ks = idx & 1;
#pragma unroll
        for (int j = 0; j < 8; ++j)
            o[j] = f2bf(Wo[(ks * 32 + quad * 8 + j) * 64 + nt * 16 + nn]);
    } else if (fid < 64) {
        int idx = fid - 32, c = idx >> 3, tile = (idx >> 1) & 3, ks = idx & 1;
#pragma unroll
        for (int j = 0; j < 8; ++j)
            o[j] = f2bf(W1[(ks * 32 + quad * 8 + j) * 256 + c * 64 + tile * 16 + nn]);
    } else {
        int idx = fid - 64, c = idx >> 3, nt = (idx >> 1) & 3, ks = idx & 1;
#pragma unroll
        for (int j = 0; j < 8; ++j)
            o[j] = f2bf(W2[(c * 64 + ks * 32 + quad * 8 + j) * 64 + nt * 16 + nn]);
    }
    *(short8*)(ws + (size_t)gid * 8) = o;
}

__global__ __launch_bounds__(256, 4) void block_kernel(
    const float* __restrict__ x,
    const float* __restrict__ bo,
    const float* __restrict__ b1,
    const float* __restrict__ b2,
    const float* __restrict__ g1, const float* __restrict__ be1,
    const float* __restrict__ g2, const float* __restrict__ be2,
    const short8* __restrict__ WB,
    float* __restrict__ out)
{
    __shared__ short sm[NSH];
    const int tid  = threadIdx.x;
    const int wv   = tid >> 6;
    const int lane = tid & 63;
    const int quad = lane >> 4;
    const int nn   = lane & 15;
    const int t_my = wv * 16 + nn;        // column-owned row index for swapped products
    const int b    = blockIdx.x;
    const float* xb = x + (size_t)b * 4096;
    const f32x4 zf = {0.f, 0.f, 0.f, 0.f};
    const short8 z8 = {0, 0, 0, 0, 0, 0, 0, 0};

    // ---------- phase 1: x -> regs (C-layout), LN1 -> h; init ones row ----------
    if (tid < ST) sm[OV + 64 * ST + tid] = (short)0x3F80;   // ones row (m=8 of PV A)
    float xr[16];                          // xr[nt*4+r] = x[16wv+quad*4+r][nt*16+nn]
    float gv[4], bv[4];
#pragma unroll
    for (int nt = 0; nt < 4; ++nt) { gv[nt] = g1[nt * 16 + nn]; bv[nt] = be1[nt * 16 + nn]; }
#pragma unroll
    for (int nt = 0; nt < 4; ++nt)
#pragma unroll
        for (int r = 0; r < 4; ++r)
            xr[nt * 4 + r] = xb[(wv * 16 + quad * 4 + r) * 64 + nt * 16 + nn];
#pragma unroll
    for (int r = 0; r < 4; ++r) {
        float s1 = 0.f, s2 = 0.f;
#pragma unroll
        for (int nt = 0; nt < 4; ++nt) { float v = xr[nt * 4 + r]; s1 += v; s2 += v * v; }
        s1 += __shfl_xor(s1, 1); s1 += __shfl_xor(s1, 2); s1 += __shfl_xor(s1, 4); s1 += __shfl_xor(s1, 8);
        s2 += __shfl_xor(s2, 1); s2 += __shfl_xor(s2, 2); s2 += __shfl_xor(s2, 4); s2 += __shfl_xor(s2, 8);
        float mu = s1 * 0.015625f;
        float rstd = rsqrtf(s2 * 0.015625f - mu * mu + 1e-5f);
        int base = OH + (wv * 16 + quad * 4 + r) * ST + nn;
#pragma unroll
        for (int nt = 0; nt < 4; ++nt)
            sm[base + nt * 16] = f2bf((xr[nt * 4 + r] - mu) * rstd * gv[nt] + bv[nt]);
    }
    // no barrier: phase 2 reads only own-wave h rows

    // ---------- phase 2: q (regs), k (LDS), vT (LDS) ----------
    unsigned qp[8];                        // qp[jt*2+p] = bf16 pair q[t_my][jt*16+quad*4+2p..+1]
    {
        short8 hf0 = *(const short8*)&sm[OH + t_my * ST + quad * 8];
        short8 hf1 = *(const short8*)&sm[OH + t_my * ST + 32 + quad * 8];
#pragma unroll
        for (int jt = 0; jt < 4; ++jt) {           // q: stays in registers
            f32x4 a = mfma16(WB[(size_t)(jt * 2 + 0) * 64 + lane], hf0, zf);
            a = mfma16(WB[(size_t)(jt * 2 + 1) * 64 + lane], hf1, a);
            qp[jt * 2 + 0] = pk2(a[0], a[1]);
            qp[jt * 2 + 1] = pk2(a[2], a[3]);
        }
#pragma unroll
        for (int jt = 0; jt < 4; ++jt) {           // k -> LDS
            f32x4 a = mfma16(WB[(size_t)((4 + jt) * 2 + 0) * 64 + lane], hf0, zf);
            a = mfma16(WB[(size_t)((4 + jt) * 2 + 1) * 64 + lane], hf1, a);
            uint2 w; w.x = pk2(a[0], a[1]); w.y = pk2(a[2], a[3]);
            *(uint2*)&sm[OKK + t_my * ST + jt * 16 + quad * 4] = w;
        }
#pragma unroll
        for (int dt = 0; dt < 4; ++dt) {           // v direct: C[t][d] -> store vT[d][t]
            f32x4 a = mfma16(hf0, WB[(size_t)((8 + dt) * 2 + 0) * 64 + lane], zf);
            a = mfma16(hf1, WB[(size_t)((8 + dt) * 2 + 1) * 64 + lane], a);
            uint2 w; w.x = pk2(a[0], a[1]); w.y = pk2(a[2], a[3]);
            *(uint2*)&sm[OV + (dt * 16 + nn) * ST + wv * 16 + quad * 4] = w;
        }
    }
    __syncthreads();   // B1: k, vT, ones row read across waves in attention

    // ---------- phase 3: attention, S^T scheme, zero barriers ----------
    const bool keep0 = (quad * 4 + 0) <= nn, keep1 = (quad * 4 + 1) <= nn;
    const bool keep2 = (quad * 4 + 2) <= nn, keep3 = (quad * 4 + 3) <= nn;
    const int arow_base = (nn < 8) ? nn : 64;      // lanes 8..15 read ones row (rows 9..15 unused)
    const int arow_step = (nn < 8) ? 8 : 0;
    const int nks = (wv < 2) ? 1 : 2;      // PV K-range: s < nks*32 covers all unmasked s
    const int zhi = nks * 2;               // P tiles that must be zeroed if not computed
#pragma unroll 1
    for (int h = 0; h < 8; ++h) {
        // build q B-frag from registers: 4 wave-uniform shfls (quads 1-3 garbage is
        // annihilated by zeroed A-side rows k>=8)
        short8 bq;
        {
            int qsA = ((h & 1) * 2) * 16 + nn, qsB = qsA + 16;
            int qi = (h >> 1) * 2;
            union { unsigned u[4]; short8 s; } bb;
            bb.u[0] = __shfl(qp[qi + 0], qsA);
            bb.u[1] = __shfl(qp[qi + 1], qsA);
            bb.u[2] = __shfl(qp[qi + 0], qsB);
            bb.u[3] = __shfl(qp[qi + 1], qsB);
            bq = bb.s;
        }
        for (int mt = 0; mt <= wv; ++mt) {         // causal: s-tiles above wv are all-masked
            short8 ak = z8;
            if (quad == 0) ak = *(const short8*)&sm[OKK + (mt * 16 + nn) * ST + h * 8];
            f32x4 s = mfma16(ak, bq, zf);          // S^T[s][t], rows s, col t=t_my
            float e0 = EXP2F(s[0]), e1 = EXP2F(s[1]), e2 = EXP2F(s[2]), e3 = EXP2F(s[3]);
            if (mt == wv) {                        // diagonal tile: apply causal mask
                e0 = keep0 ? e0 : 0.f; e1 = keep1 ? e1 : 0.f;
                e2 = keep2 ? e2 : 0.f; e3 = keep3 ? e3 : 0.f;
            }
            uint2 w; w.x = pk2(e0, e1); w.y = pk2(e2, e3);
            *(uint2*)&sm[OP + t_my * ST + mt * 16 + quad * 4] = w;
        }
        for (int mt = wv + 1; mt < zhi; ++mt) {    // zero tiles PV will read
            uint2 w; w.x = 0u; w.y = 0u;
            *(uint2*)&sm[OP + t_my * ST + mt * 16 + quad * 4] = w;
        }
        // PV: A = vT rows (d<8) + ones row (m=8) -> C row 8 = row-sum (denominator)
        const int arow = arow_base + h * arow_step;
        f32x4 pv = zf;
        for (int ks = 0; ks < nks; ++ks) {
            short8 av = *(const short8*)&sm[OV + arow * ST + ks * 32 + quad * 8];
            short8 bp = *(const short8*)&sm[OP + t_my * ST + ks * 32 + quad * 8];
            pv = mfma16(av, bp, pv);
        }
        float denom = __shfl(pv[0], 32 + nn);      // row m=8 lives at quad 2, reg 0
        float rd = RCPF(denom);
        if (quad < 2) {                            // valid d = quad*4+r in 0..7
            uint2 w; w.x = pk2(pv[0] * rd, pv[1] * rd); w.y = pk2(pv[2] * rd, pv[3] * rd);
            *(uint2*)&sm[OH + t_my * ST + h * 8 + quad * 4] = w;   // a16[t][h*8+d]
        }
    }

    // ---------- phase 4: Wo + residual + LN2 (all wave-private; no barrier) ----------
    {
        short8 aa0 = *(const short8*)&sm[OH + t_my * ST + quad * 8];
        short8 aa1 = *(const short8*)&sm[OH + t_my * ST + 32 + quad * 8];
#pragma unroll
        for (int nt = 0; nt < 4; ++nt) {
            f32x4 oa = mfma16(aa0, WB[(size_t)(24 + nt * 2 + 0) * 64 + lane], zf);
            oa = mfma16(aa1, WB[(size_t)(24 + nt * 2 + 1) * 64 + lane], oa);
            float bov = bo[nt * 16 + nn];
#pragma unroll
            for (int r = 0; r < 4; ++r) xr[nt * 4 + r] += oa[r] + bov;
        }
    }
#pragma unroll
    for (int nt = 0; nt < 4; ++nt) { gv[nt] = g2[nt * 16 + nn]; bv[nt] = be2[nt * 16 + nn]; }
#pragma unroll
    for (int r = 0; r < 4; ++r) {
        float s1 = 0.f, s2 = 0.f;
#pragma unroll
        for (int nt = 0; nt < 4; ++nt) { float v = xr[nt * 4 + r]; s1 += v; s2 += v * v; }
        s1 += __shfl_xor(s1, 1); s1 += __shfl_xor(s1, 2); s1 += __shfl_xor(s1, 4); s1 += __shfl_xor(s1, 8);
        s2 += __shfl_xor(s2, 1); s2 += __shfl_xor(s2, 2); s2 += __shfl_xor(s2, 4); s2 += __shfl_xor(s2, 8);
        float mu = s1 * 0.015625f;
        float rstd = rsqrtf(s2 * 0.015625f - mu * mu + 1e-5f);
        int base = OP + (wv * 16 + quad * 4 + r) * ST + nn;   // h2 into dead P region
#pragma unroll
        for (int nt = 0; nt < 4; ++nt)
            sm[base + nt * 16] = f2bf((xr[nt * 4 + r] - mu) * rstd * gv[nt] + bv[nt]);
    }
    // h2 rows are wave-private: read own row, then barrier before u overlays k/vT
    short8 h2f0 = *(const short8*)&sm[OP + t_my * ST + quad * 8];
    short8 h2f1 = *(const short8*)&sm[OP + t_my * ST + 32 + quad * 8];
    __syncthreads();   // B2: u overlays k/vT; all waves done with attention reads

    // ---------- phase 5: FF in 2 K-chunks of 128 (u rows wave-private) ----------
    f32x4 fa[4];
#pragma unroll
    for (int nt = 0; nt < 4; ++nt) fa[nt] = zf;
#pragma unroll
    for (int c = 0; c < 2; ++c) {
        // FF1 chunk: u cols c*128 .. c*128+127 (8 tiles of 16)
#pragma unroll
        for (int tile = 0; tile < 8; ++tile) {
            int gc = c * 8 + tile;                 // global 16-col tile
            int fid = 32 + (gc >> 2) * 8 + (gc & 3) * 2;
            f32x4 u = mfma16(WB[(size_t)fid * 64 + lane], h2f0, zf);
            u = mfma16(WB[(size_t)(fid + 1) * 64 + lane], h2f1, u);
            const float4 bb = *(const float4*)&b1[gc * 16 + quad * 4];
            float u0 = fmaxf(u[0] + bb.x, 0.f), u1 = fmaxf(u[1] + bb.y, 0.f);
            float u2 = fmaxf(u[2] + bb.z, 0.f), u3 = fmaxf(u[3] + bb.w, 0.f);
            uint2 w; w.x = pk2(u0, u1); w.y = pk2(u2, u3);
            *(uint2*)&sm[OU + t_my * STU + tile * 16 + quad * 4] = w;
        }
        // FF2 partial over this chunk (reads own u rows; no barrier)
#pragma unroll
        for (int ks = 0; ks < 4; ++ks) {
            short8 au = *(const short8*)&sm[OU + t_my * STU + ks * 32 + quad * 8];
            int gk = c * 4 + ks;                   // global 32-row slice of W2
            int fidb = 64 + (gk >> 1) * 8 + (gk & 1);
#pragma unroll
            for (int nt = 0; nt < 4; ++nt)
                fa[nt] = mfma16(au, WB[(size_t)(fidb + nt * 2) * 64 + lane], fa[nt]);
        }
    }

    // ---------- phase 6: out = xr + ff + b2 ----------
    float* ob = out + (size_t)b * 4096;
#pragma unroll
    for (int nt = 0; nt < 4; ++nt) {
        float b2v = b2[nt * 16 + nn];
#pragma unroll
        for (int r = 0; r < 4; ++r)
            ob[(wv * 16 + quad * 4 + r) * 64 + nt * 16 + nn] = xr[nt * 4 + r] + fa[nt][r] + b2v;
    }
}

extern "C" void kernel_launch(void* const* d_in, const int* in_sizes, int n_in,
                              void* d_out, int out_size, void* d_ws, size_t ws_size,
                              hipStream_t stream) {
    const float* x   = (const float*)d_in[0];
    const float* Wq  = (const float*)d_in[1];
    const float* Wk  = (const float*)d_in[2];
    const float* Wv  = (const float*)d_in[3];
    const float* Wo  = (const float*)d_in[4];
    const float* bo  = (const float*)d_in[5];
    const float* W1  = (const float*)d_in[6];
    const float* b1  = (const float*)d_in[7];
    const float* W2  = (const float*)d_in[8];
    const float* b2  = (const float*)d_in[9];
    const float* g1  = (const float*)d_in[10];
    const float* be1 = (const float*)d_in[11];
    const float* g2  = (const float*)d_in[12];
    const float* be2 = (const float*)d_in[13];
    short* ws = (short*)d_ws;
    prepack_kernel<<<dim3(96), dim3(64), 0, stream>>>(Wq, Wk, Wv, Wo, W1, W2, ws);
    const int nb = in_sizes[0] / 4096;
    block_kernel<<<dim3(nb), dim3(256), 0, stream>>>(
        x, bo, b1, b2, g1, be1, g2, be2, (const short8*)ws, (float*)d_out);
}